// Round 1
// baseline (2747.246 us; speedup 1.0000x reference)
//
#include <hip/hip_runtime.h>
#include <math.h>

#define B_ 32
#define C_ 256
#define H_ 28
#define W_ 28
#define NPIX 784
#define HK 14
#define NKPIX 196
#define CM 1024
#define NHEADS 8
#define DKV 32
#define EPS_ 1e-5f

__device__ __forceinline__ float gelu_f(float x) {
    return 0.5f * x * (1.0f + erff(x * 0.70710678118654752f));
}

// ---------------- 1. LPU: depthwise 3x3 + bias + residual ----------------
__global__ void lpu_kernel(const float* __restrict__ x, const float* __restrict__ w,
                           const float* __restrict__ bias, float* __restrict__ out) {
    int idx = blockIdx.x * blockDim.x + threadIdx.x;
    if (idx >= B_ * C_ * NPIX) return;
    int p = idx % NPIX;
    int c = (idx / NPIX) % C_;
    int b = idx / (NPIX * C_);
    int y = p / W_, xx = p % W_;
    const float* xb = x + ((size_t)b * C_ + c) * NPIX;
    const float* wc = w + c * 9;
    float acc = bias[c] + x[idx];  // conv bias + residual
    #pragma unroll
    for (int dy = -1; dy <= 1; ++dy) {
        int yy = y + dy;
        if (yy < 0 || yy >= H_) continue;
        #pragma unroll
        for (int dx = -1; dx <= 1; ++dx) {
            int xc = xx + dx;
            if (xc < 0 || xc >= W_) continue;
            acc += wc[(dy + 1) * 3 + (dx + 1)] * xb[yy * W_ + xc];
        }
    }
    out[idx] = acc;
}

// ---------------- 2. LayerNorm over (C,H,W) per sample: stats ----------------
__global__ void ln_stats_kernel(const float* __restrict__ x, float* __restrict__ mean,
                                float* __restrict__ rstd) {
    int b = blockIdx.x;
    const float* xb = x + (size_t)b * (C_ * NPIX);
    float s = 0.f, s2 = 0.f;
    for (int i = threadIdx.x; i < C_ * NPIX; i += 256) {
        float v = xb[i];
        s += v; s2 += v * v;
    }
    __shared__ float ss[256], ss2[256];
    ss[threadIdx.x] = s; ss2[threadIdx.x] = s2;
    __syncthreads();
    for (int off = 128; off > 0; off >>= 1) {
        if (threadIdx.x < off) {
            ss[threadIdx.x] += ss[threadIdx.x + off];
            ss2[threadIdx.x] += ss2[threadIdx.x + off];
        }
        __syncthreads();
    }
    if (threadIdx.x == 0) {
        const float inv_n = 1.0f / (C_ * NPIX);
        float m = ss[0] * inv_n;
        float var = ss2[0] * inv_n - m * m;
        mean[b] = m;
        rstd[b] = rsqrtf(var + EPS_);
    }
}

__global__ void ln_apply_kernel(const float* __restrict__ x, const float* __restrict__ mean,
                                const float* __restrict__ rstd, float* __restrict__ out) {
    int idx = blockIdx.x * blockDim.x + threadIdx.x;
    if (idx >= B_ * C_ * NPIX) return;
    int b = idx / (C_ * NPIX);
    out[idx] = (x[idx] - mean[b]) * rstd[b];
}

// ---------------- 3. q/k/v projection: out[b,h,p,d] = in[b,:,p] @ W.T + bias ----------------
// in layout: [b, C, NP]; W: [256, 256] row-major (out, in); out: [b, 8, NP, 32]
template <int NP>
__global__ void proj_qkv_kernel(const float* __restrict__ in, const float* __restrict__ Wt,
                                const float* __restrict__ bias, float* __restrict__ out) {
    const int P = 8;
    const int TILES = (NP + P - 1) / P;
    int tile = blockIdx.x % TILES;
    int b = blockIdx.x / TILES;
    int p0 = tile * P;
    __shared__ float xs[C_][P + 1];
    int t = threadIdx.x;
    const float* inb = in + ((size_t)b * C_ + t) * NP;
    #pragma unroll
    for (int p = 0; p < P; ++p)
        xs[t][p] = (p0 + p < NP) ? inb[p0 + p] : 0.f;
    __syncthreads();
    float acc[P] = {0, 0, 0, 0, 0, 0, 0, 0};
    const float* wrow = Wt + (size_t)t * C_;
    for (int c = 0; c < C_; ++c) {
        float wv = wrow[c];
        #pragma unroll
        for (int p = 0; p < P; ++p) acc[p] += xs[c][p] * wv;
    }
    int h = t >> 5, d = t & 31;
    float bv = bias[t];
    #pragma unroll
    for (int p = 0; p < P; ++p) {
        if (p0 + p < NP)
            out[(((size_t)b * NHEADS + h) * NP + (p0 + p)) * DKV + d] = acc[p] + bv;
    }
}

// ---------------- 4. kv depthwise 2x2 stride-2 conv ----------------
__global__ void kvconv_kernel(const float* __restrict__ x, const float* __restrict__ w,
                              const float* __restrict__ bias, float* __restrict__ out) {
    int idx = blockIdx.x * blockDim.x + threadIdx.x;
    if (idx >= B_ * C_ * NKPIX) return;
    int p = idx % NKPIX;
    int c = (idx / NKPIX) % C_;
    int b = idx / (NKPIX * C_);
    int yo = p / HK, xo = p % HK;
    const float* xb = x + ((size_t)b * C_ + c) * NPIX;
    const float* wc = w + c * 4;
    float acc = bias[c];
    #pragma unroll
    for (int dy = 0; dy < 2; ++dy)
        #pragma unroll
        for (int dx = 0; dx < 2; ++dx)
            acc += wc[dy * 2 + dx] * xb[(2 * yo + dy) * W_ + (2 * xo + dx)];
    out[idx] = acc;
}

// ---------------- 5. attention: online softmax, 1 query/thread ----------------
// q: [b,8,784,32], k/v: [b,8,196,32], pos_b: [8,784,196], out tmp: [b,784,256]
__global__ void attn_kernel(const float* __restrict__ q, const float* __restrict__ k,
                            const float* __restrict__ v, const float* __restrict__ pos_b,
                            float* __restrict__ out) {
    int qb = blockIdx.x % 4;
    int h = (blockIdx.x / 4) % NHEADS;
    int b = blockIdx.x / (4 * NHEADS);
    __shared__ float ks[NKPIX * DKV];
    __shared__ float vs[NKPIX * DKV];
    const float* kbp = k + ((size_t)(b * NHEADS + h)) * NKPIX * DKV;
    const float* vbp = v + ((size_t)(b * NHEADS + h)) * NKPIX * DKV;
    for (int i = threadIdx.x; i < NKPIX * DKV; i += 256) {
        ks[i] = kbp[i];
        vs[i] = vbp[i];
    }
    __syncthreads();
    if (threadIdx.x >= 196) return;
    int iq = qb * 196 + threadIdx.x;
    float qr[DKV];
    const float* qp = q + (((size_t)(b * NHEADS + h)) * NPIX + iq) * DKV;
    #pragma unroll
    for (int d = 0; d < DKV; ++d) qr[d] = qp[d];
    const float* pb = pos_b + ((size_t)h * NPIX + iq) * NKPIX;
    float m = -1e30f, l = 0.f;
    float o[DKV];
    #pragma unroll
    for (int d = 0; d < DKV; ++d) o[d] = 0.f;
    const float scale = 0.17677669529663689f;  // 1/sqrt(32)
    for (int j = 0; j < NKPIX; ++j) {
        float s = 0.f;
        const float* kj = &ks[j * DKV];
        #pragma unroll
        for (int d = 0; d < DKV; ++d) s += qr[d] * kj[d];
        s = s * scale + pb[j];
        float nm = fmaxf(m, s);
        float alpha = __expf(m - nm);
        float pexp = __expf(s - nm);
        l = l * alpha + pexp;
        const float* vj = &vs[j * DKV];
        #pragma unroll
        for (int d = 0; d < DKV; ++d) o[d] = o[d] * alpha + pexp * vj[d];
        m = nm;
    }
    float inv = 1.f / l;
    float* op = out + ((size_t)b * NPIX + iq) * C_ + h * DKV;
    #pragma unroll
    for (int d = 0; d < DKV; ++d) op[d] = o[d] * inv;
}

// ---------------- 6. wo projection + flat-reinterpret residual ----------------
// in tmp: [b,784,256]; out x2[flat] = tmp@wo.T + bo + x1[flat]  (the .view trick = flat add)
__global__ void proj_wo_kernel(const float* __restrict__ in, const float* __restrict__ Wt,
                               const float* __restrict__ bias, const float* __restrict__ res,
                               float* __restrict__ out) {
    const int P = 8;
    int tile = blockIdx.x % (NPIX / P);
    int b = blockIdx.x / (NPIX / P);
    int p0 = tile * P;
    __shared__ float xs[C_][P + 1];
    int t = threadIdx.x;
    #pragma unroll
    for (int p = 0; p < P; ++p)
        xs[t][p] = in[((size_t)b * NPIX + p0 + p) * C_ + t];  // coalesced over t
    __syncthreads();
    float acc[P] = {0, 0, 0, 0, 0, 0, 0, 0};
    const float* wrow = Wt + (size_t)t * C_;
    for (int c = 0; c < C_; ++c) {
        float wv = wrow[c];
        #pragma unroll
        for (int p = 0; p < P; ++p) acc[p] += xs[c][p] * wv;
    }
    float bv = bias[t];
    #pragma unroll
    for (int p = 0; p < P; ++p) {
        size_t idx = ((size_t)b * NPIX + p0 + p) * C_ + t;
        out[idx] = acc[p] + bv + res[idx];
    }
}

// ---------------- 7. IRFFN conv1 1x1 (C->Cm) + BN + GELU ----------------
// in t1: [b, C, 784]; out t2: [b, Cm, 784]
__global__ void conv1_kernel(const float* __restrict__ in, const float* __restrict__ Wt,
                             const float* __restrict__ bias,
                             const float* __restrict__ g, const float* __restrict__ bb,
                             const float* __restrict__ mm, const float* __restrict__ vv,
                             float* __restrict__ out) {
    const int P = 16;
    int tile = blockIdx.x % (NPIX / P);  // 49
    int b = blockIdx.x / (NPIX / P);
    int p0 = tile * P;
    __shared__ float xs[C_][P + 1];
    int t = threadIdx.x;
    const float* inb = in + ((size_t)b * C_ + t) * NPIX + p0;
    #pragma unroll
    for (int p = 0; p < P; ++p) xs[t][p] = inb[p];
    __syncthreads();
    float acc[4][P];
    #pragma unroll
    for (int j = 0; j < 4; ++j)
        #pragma unroll
        for (int p = 0; p < P; ++p) acc[j][p] = 0.f;
    for (int c = 0; c < C_; ++c) {
        float w0 = Wt[(size_t)t * C_ + c];
        float w1 = Wt[((size_t)t + 256) * C_ + c];
        float w2 = Wt[((size_t)t + 512) * C_ + c];
        float w3 = Wt[((size_t)t + 768) * C_ + c];
        #pragma unroll
        for (int p = 0; p < P; ++p) {
            float xv = xs[c][p];
            acc[0][p] += xv * w0;
            acc[1][p] += xv * w1;
            acc[2][p] += xv * w2;
            acc[3][p] += xv * w3;
        }
    }
    #pragma unroll
    for (int j = 0; j < 4; ++j) {
        int oc = t + j * 256;
        float sc = g[oc] * rsqrtf(vv[oc] + EPS_);
        float sh = bb[oc] - mm[oc] * sc;
        float cb = bias[oc];
        float* ob = out + ((size_t)b * CM + oc) * NPIX + p0;
        #pragma unroll
        for (int p = 0; p < P; ++p) {
            float y = (acc[j][p] + cb) * sc + sh;
            ob[p] = gelu_f(y);
        }
    }
}

// ---------------- 8. FFN tail fused: dw3x3+BN+GELU+conv2 1x1+BN+residual ----------------
// block = (b, row y); 256 threads = out channels; chunks of 32 cm staged in LDS
__global__ void ffn2_kernel(const float* __restrict__ t2, const float* __restrict__ dww,
                            const float* __restrict__ dwb,
                            const float* __restrict__ g2, const float* __restrict__ b2,
                            const float* __restrict__ m2, const float* __restrict__ v2,
                            const float* __restrict__ W2, const float* __restrict__ c2b,
                            const float* __restrict__ g3, const float* __restrict__ b3,
                            const float* __restrict__ m3, const float* __restrict__ v3,
                            const float* __restrict__ x2, float* __restrict__ out) {
    int y = blockIdx.x % H_;
    int b = blockIdx.x / H_;
    const int CK = 32;
    __shared__ float s[CK][W_];
    float acc[W_];
    #pragma unroll
    for (int p = 0; p < W_; ++p) acc[p] = 0.f;
    int t = threadIdx.x;
    for (int cm0 = 0; cm0 < CM; cm0 += CK) {
        for (int idx = t; idx < CK * W_; idx += 256) {
            int cl = idx / W_, xx = idx % W_;
            int cm = cm0 + cl;
            const float* tb = t2 + ((size_t)b * CM + cm) * NPIX;
            const float* wc = dww + cm * 9;
            float a = dwb[cm];
            #pragma unroll
            for (int dy = -1; dy <= 1; ++dy) {
                int yy = y + dy;
                if (yy < 0 || yy >= H_) continue;
                #pragma unroll
                for (int dx = -1; dx <= 1; ++dx) {
                    int xc = xx + dx;
                    if (xc < 0 || xc >= W_) continue;
                    a += wc[(dy + 1) * 3 + (dx + 1)] * tb[yy * W_ + xc];
                }
            }
            float sc = g2[cm] * rsqrtf(v2[cm] + EPS_);
            float sh = b2[cm] - m2[cm] * sc;
            s[cl][xx] = gelu_f(a * sc + sh);
        }
        __syncthreads();
        const float* wrow = W2 + (size_t)t * CM + cm0;
        #pragma unroll 8
        for (int cl = 0; cl < CK; ++cl) {
            float wv = wrow[cl];
            #pragma unroll
            for (int xx = 0; xx < W_; ++xx) acc[xx] += s[cl][xx] * wv;
        }
        __syncthreads();
    }
    float sc = g3[t] * rsqrtf(v3[t] + EPS_);
    float sh = b3[t] - m3[t] * sc;
    float cb = c2b[t];
    size_t base = ((size_t)b * C_ + t) * NPIX + (size_t)y * W_;
    #pragma unroll
    for (int xx = 0; xx < W_; ++xx) {
        float yv = (acc[xx] + cb) * sc + sh;
        out[base + xx] = x2[base + xx] + yv;
    }
}

extern "C" void kernel_launch(void* const* d_in, const int* in_sizes, int n_in,
                              void* d_out, int out_size, void* d_ws, size_t ws_size,
                              hipStream_t stream) {
    const float* x     = (const float*)d_in[0];
    const float* lpu_w = (const float*)d_in[1];
    const float* lpu_b = (const float*)d_in[2];
    const float* dw_w  = (const float*)d_in[3];
    const float* dw_b  = (const float*)d_in[4];
    const float* wq    = (const float*)d_in[5];
    const float* bq    = (const float*)d_in[6];
    const float* wk    = (const float*)d_in[7];
    const float* bk    = (const float*)d_in[8];
    const float* wv    = (const float*)d_in[9];
    const float* bv    = (const float*)d_in[10];
    const float* wo    = (const float*)d_in[11];
    const float* bo    = (const float*)d_in[12];
    const float* posb  = (const float*)d_in[13];
    const float* c1_w  = (const float*)d_in[14];
    const float* c1_b  = (const float*)d_in[15];
    const float* bn1_g = (const float*)d_in[16];
    const float* bn1_b = (const float*)d_in[17];
    const float* bn1_m = (const float*)d_in[18];
    const float* bn1_v = (const float*)d_in[19];
    const float* dw2_w = (const float*)d_in[20];
    const float* dw2_b = (const float*)d_in[21];
    const float* bn2_g = (const float*)d_in[22];
    const float* bn2_b = (const float*)d_in[23];
    const float* bn2_m = (const float*)d_in[24];
    const float* bn2_v = (const float*)d_in[25];
    const float* c2_w  = (const float*)d_in[26];
    const float* c2_b  = (const float*)d_in[27];
    const float* bn3_g = (const float*)d_in[28];
    const float* bn3_b = (const float*)d_in[29];
    const float* bn3_m = (const float*)d_in[30];
    const float* bn3_v = (const float*)d_in[31];

    float* ws = (float*)d_ws;
    const size_t n1  = (size_t)B_ * C_ * NPIX;    // 6,422,528
    const size_t nkv = (size_t)B_ * C_ * NKPIX;   // 1,605,632
    const size_t nm  = (size_t)B_ * CM * NPIX;    // 25,690,112

    float* x1  = ws;                 // LPU out, later reused as t1
    float* xn  = ws + n1;            // LN1 out, later reused as attn tmp
    float* qb  = ws + 2 * n1;        // q, later reused as x2
    float* kvb = ws + 3 * n1;
    float* kb  = kvb + nkv;
    float* vb  = kb + nkv;
    float* t2  = ws + 3 * n1 + 3 * nkv;
    float* stats = t2 + nm;          // [mean1(32), rstd1(32), mean2(32), rstd2(32)]
    float* tmp = xn;
    float* x2  = qb;
    float* t1  = x1;
    float* outp = (float*)d_out;

    int eb = (int)((n1 + 255) / 256);
    lpu_kernel<<<eb, 256, 0, stream>>>(x, lpu_w, lpu_b, x1);
    ln_stats_kernel<<<B_, 256, 0, stream>>>(x1, stats, stats + 32);
    ln_apply_kernel<<<eb, 256, 0, stream>>>(x1, stats, stats + 32, xn);
    proj_qkv_kernel<NPIX><<<B_ * (NPIX / 8), 256, 0, stream>>>(xn, wq, bq, qb);
    kvconv_kernel<<<(int)((nkv + 255) / 256), 256, 0, stream>>>(x1, dw_w, dw_b, kvb);
    proj_qkv_kernel<NKPIX><<<B_ * ((NKPIX + 7) / 8), 256, 0, stream>>>(kvb, wk, bk, kb);
    proj_qkv_kernel<NKPIX><<<B_ * ((NKPIX + 7) / 8), 256, 0, stream>>>(kvb, wv, bv, vb);
    attn_kernel<<<B_ * NHEADS * 4, 256, 0, stream>>>(qb, kb, vb, posb, tmp);
    proj_wo_kernel<<<B_ * (NPIX / 8), 256, 0, stream>>>(tmp, wo, bo, x1, x2);
    ln_stats_kernel<<<B_, 256, 0, stream>>>(x2, stats + 64, stats + 96);
    ln_apply_kernel<<<eb, 256, 0, stream>>>(x2, stats + 64, stats + 96, t1);
    conv1_kernel<<<B_ * (NPIX / 16), 256, 0, stream>>>(t1, c1_w, c1_b, bn1_g, bn1_b, bn1_m, bn1_v, t2);
    ffn2_kernel<<<B_ * H_, 256, 0, stream>>>(t2, dw2_w, dw2_b, bn2_g, bn2_b, bn2_m, bn2_v,
                                             c2_w, c2_b, bn3_g, bn3_b, bn3_m, bn3_v, x2, outp);
}